// Round 9
// baseline (1063.473 us; speedup 1.0000x reference)
//
#include <hip/hip_runtime.h>

#define B_ 256
#define T_ 512
#define I_ 64
#define H_ 512
#define O_ 16

typedef _Float16 half8 __attribute__((ext_vector_type(8)));
typedef _Float16 half4 __attribute__((ext_vector_type(4)));
typedef float    f32x4 __attribute__((ext_vector_type(4)));

#define MFMA16(a, b, c) __builtin_amdgcn_mfma_f32_16x16x32_f16((a), (b), (c), 0, 0, 0)

__device__ inline half8 cvt_h8(f32x4 a, f32x4 b) {
  half8 v;
  v[0] = (_Float16)a[0]; v[1] = (_Float16)a[1]; v[2] = (_Float16)a[2]; v[3] = (_Float16)a[3];
  v[4] = (_Float16)b[0]; v[5] = (_Float16)b[1]; v[6] = (_Float16)b[2]; v[7] = (_Float16)b[3];
  return v;
}

// ---------------- prepass: xp = W_ih @ x_t^T + b  (D-layout: col=batch, row=j) ----
// Stored f16 in EXACT consumer order for the 512-thread main kernel:
// consumer thread tid_c = w*64 + kq*16 + n covers j = w*64 + ln*16 + 4kq + i
// (ln 0..3), batch = g*16 + n. Half-index = ((t*16+g)*512 + tid_c)*16 + ln*4 + i.
__global__ __launch_bounds__(256, 2)
void xp_prepass(const float* __restrict__ x, const float* __restrict__ W_ih,
                const float* __restrict__ b_ih, const float* __restrict__ b_hh,
                _Float16* __restrict__ xp) {
  const int tid = threadIdx.x, L = tid & 63, w = tid >> 6;
  const int n = L & 15, kq = (L >> 4) & 3;
  const int g = blockIdx.x & 15, tc = blockIdx.x >> 4;   // 512 blocks = 16 g x 32 tc

  __shared__ __attribute__((aligned(16))) _Float16 wlih[32 * 2 * 64 * 8]; // 64 KB A-frags
  __shared__ float biasl[512];
  const half8* wlih8 = (const half8*)wlih;

  #pragma unroll
  for (int u = 0; u < 16; ++u) {
    const int s = tid + u * 256;                 // [0,4096)
    const int jt = s >> 7, c = (s >> 6) & 1, Lp = s & 63;
    const int jl = Lp & 15, kq2 = Lp >> 4;
    const float* p = W_ih + (jt * 16 + jl) * I_ + c * 32 + kq2 * 8;
    ((half8*)wlih)[s] = cvt_h8(*(const f32x4*)(p), *(const f32x4*)(p + 4));
  }
  #pragma unroll
  for (int u = 0; u < 2; ++u) {
    const int idx = tid + u * 256;
    biasl[idx] = b_ih[idx] + b_hh[idx];
  }
  __syncthreads();

  half8 xb[4][2];
  #pragma unroll
  for (int rr = 0; rr < 4; ++rr) {
    const int t = tc * 16 + w * 4 + rr;
    const float* p = x + ((size_t)(g * 16 + n) * T_ + t) * I_ + kq * 8;
    xb[rr][0] = cvt_h8(*(const f32x4*)(p),      *(const f32x4*)(p + 4));
    xb[rr][1] = cvt_h8(*(const f32x4*)(p + 32), *(const f32x4*)(p + 36));
  }

  #pragma unroll 1
  for (int hi = 0; hi < 8; ++hi) {             // consumer wave index
    half8 o[4][2];
    #pragma unroll
    for (int jt2 = 0; jt2 < 4; ++jt2) {        // consumer ln
      const int jt = hi * 4 + jt2;
      const half8 a0 = wlih8[(jt * 2 + 0) * 64 + L];
      const half8 a1 = wlih8[(jt * 2 + 1) * 64 + L];
      const f32x4 bv = *(const f32x4*)&biasl[jt * 16 + 4 * kq];
      #pragma unroll
      for (int rr = 0; rr < 4; ++rr) {
        f32x4 acc; acc[0] = 0.f; acc[1] = 0.f; acc[2] = 0.f; acc[3] = 0.f;
        acc = MFMA16(a0, xb[rr][0], acc);
        acc = MFMA16(a1, xb[rr][1], acc);
        #pragma unroll
        for (int i = 0; i < 4; ++i)
          o[rr][jt2 >> 1][(jt2 & 1) * 4 + i] = (_Float16)(acc[i] + bv[i]);
      }
    }
    #pragma unroll
    for (int rr = 0; rr < 4; ++rr) {
      const int t = tc * 16 + w * 4 + rr;
      _Float16* dst = xp + ((size_t)(t * 16 + g) * 512 + hi * 64 + L) * 16;
      *(half8*)(dst)     = o[rr][0];
      *(half8*)(dst + 8) = o[rr][1];
    }
  }
}

// ---------------- main loop body, templated on wave id (static rotation) ----------
// Wave W visits kc in order (2W+p)&15, p=0..15 — every LDS offset is a
// compile-time immediate. p=0 is kc=2W: the slice THIS wave wrote last step,
// re-read pre-barrier into bq0 (same-wave DS ordering) to cover the
// post-barrier LDS cold start. Weight storage by p: 0..7 AGPR (pinned),
// 8..12 arch VGPR, 13..15 LDS (per-wave private region).
template <int W>
__device__ __forceinline__ void rnn_core(const float* __restrict__ W_hh,
                                         const _Float16* __restrict__ xp,
                                         half8* hb8, half8* wl8w,
                                         const int g, const int L) {
  const int n  = L & 15;
  const int kq = (L >> 4) & 3;
  const int tid = W * 64 + L;

  half8 whA[32];   // p 0..7  -> 128 AGPR (class-pinned)
  half8 whV[20];   // p 8..12 -> 80 arch VGPR
  #pragma unroll
  for (int ln = 0; ln < 4; ++ln) {
    const int j = W * 64 + ln * 16 + n;
    #pragma unroll
    for (int p = 0; p < 8; ++p) {
      const int kc = (2 * W + p) & 15;
      const f32x4* s = (const f32x4*)(W_hh + j * H_ + kc * 32 + kq * 8);
      whA[ln * 8 + p] = cvt_h8(s[0], s[1]);
    }
    #pragma unroll
    for (int p = 8; p < 13; ++p) {
      const int kc = (2 * W + p) & 15;
      const f32x4* s = (const f32x4*)(W_hh + j * H_ + kc * 32 + kq * 8);
      whV[ln * 5 + (p - 8)] = cvt_h8(s[0], s[1]);
    }
    #pragma unroll
    for (int p = 13; p < 16; ++p) {
      const int kc = (2 * W + p) & 15;
      const f32x4* s = (const f32x4*)(W_hh + j * H_ + kc * 32 + kq * 8);
      wl8w[((p - 13) * 4 + ln) * 64 + L] = cvt_h8(s[0], s[1]);
    }
  }
  #pragma unroll
  for (int i2 = 0; i2 < 32; ++i2) asm volatile("" : "+a"(whA[i2]));

  // xp for t=0
  half8 xq0, xq1;
  {
    const half8* p0 = (const half8*)(xp + ((size_t)(0 * 16 + g) * 512 + tid) * 16);
    xq0 = p0[0]; xq1 = p0[1];
  }

  half8* rb = hb8;          // read buffer (t even -> buffer 0)
  half8* wb = hb8 + 1024;   // write buffer
  half8 bq0 = rb[((2 * W) & 15) * 64 + L];   // p=0 pre-read (h0 staged+barriered)

  #pragma unroll 1
  for (int t = 0; t < T_; ++t) {
    // acc init from xp: acc[ln][i] for row j = W*64 + ln*16 + 4kq + i, col n
    f32x4 acc[4];
    #pragma unroll
    for (int ln = 0; ln < 4; ++ln)
      #pragma unroll
      for (int i = 0; i < 4; ++i)
        acc[ln][i] = (float)((ln < 2 ? xq0 : xq1)[(ln & 1) * 4 + i]);

    // prefetch xp for t+1 (in flight across the MFMA wall)
    {
      const int tn = (t + 1) & (T_ - 1);
      const half8* pn = (const half8*)(xp + ((size_t)(tn * 16 + g) * 512 + tid) * 16);
      xq0 = pn[0]; xq1 = pn[1];
    }

    // p = 0: own kc, already in registers
    #pragma unroll
    for (int ln = 0; ln < 4; ++ln) acc[ln] = MFMA16(whA[ln * 8 + 0], bq0, acc[ln]);
    // p = 1..7: AGPR weights
    #pragma unroll
    for (int p = 1; p < 8; ++p) {
      const half8 b = rb[((2 * W + p) & 15) * 64 + L];
      #pragma unroll
      for (int ln = 0; ln < 4; ++ln) acc[ln] = MFMA16(whA[ln * 8 + p], b, acc[ln]);
    }
    // p = 8..12: VGPR weights
    #pragma unroll
    for (int p = 8; p < 13; ++p) {
      const half8 b = rb[((2 * W + p) & 15) * 64 + L];
      #pragma unroll
      for (int ln = 0; ln < 4; ++ln) acc[ln] = MFMA16(whV[ln * 5 + (p - 8)], b, acc[ln]);
    }
    // p = 13..15: LDS weights
    #pragma unroll
    for (int p = 13; p < 16; ++p) {
      const half8 b = rb[((2 * W + p) & 15) * 64 + L];
      #pragma unroll
      for (int ln = 0; ln < 4; ++ln)
        acc[ln] = MFMA16(wl8w[((p - 13) * 4 + ln) * 64 + L], b, acc[ln]);
    }

    // epilogue: relu -> b64 writes into wb.
    // thread covers j = W*64 + ln*16 + 4kq + i, col n:
    // half8 slot S = (W*8 + ln*2 + (kq>>1))*16 + n, half-offset 4*(kq&1)
    #pragma unroll
    for (int ln = 0; ln < 4; ++ln) {
      half4 hv;
      #pragma unroll
      for (int i = 0; i < 4; ++i) hv[i] = (_Float16)fmaxf(acc[ln][i], 0.f);
      const int S = (W * 8 + ln * 2 + (kq >> 1)) * 16 + n;
      *(half4*)((_Float16*)wb + S * 8 + 4 * (kq & 1)) = hv;
    }
    // pre-barrier self-read of next step's p=0 (own writes; same-wave DS order)
    bq0 = wb[((2 * W) & 15) * 64 + L];

    __syncthreads();   // one barrier per step
    half8* tmp = rb; rb = wb; wb = tmp;
  }
}

// ---------------- main persistent RNN (TLP + static wave phase rotation) ----------
// 16 blocks x 512 threads (8 waves, 2/SIMD, 256 unified regs/wave). Wave w owns
// j in [64w, 64w+64). Template dispatch by wave id makes the kc rotation free.
__global__ __launch_bounds__(512, 2)
void rnn_persist(const float* __restrict__ h0, const float* __restrict__ W_hh,
                 const float* __restrict__ W_fc, const float* __restrict__ b_fc,
                 float* __restrict__ out, const _Float16* __restrict__ xp) {
  const int tid = threadIdx.x;
  const int L   = tid & 63;
  const int w   = tid >> 6;        // wave 0..7
  const int g   = blockIdx.x;      // batches [16g, 16g+16)

  __shared__ __attribute__((aligned(16))) _Float16 hb[2 * 16 * 64 * 8];   // 32 KB
  __shared__ __attribute__((aligned(16))) _Float16 wlds[8 * 12 * 64 * 8]; // 96 KB
  half8* hb8 = (half8*)hb;

  // ---- h(0) into B-layout buffer 0: half8 slot S = k8*16 + nb ----
  #pragma unroll
  for (int u = 0; u < 2; ++u) {
    const int S = tid + u * 512;                 // [0,1024)
    const int k8 = S >> 4, nb = S & 15;
    const float* p = h0 + (g * 16 + nb) * H_ + k8 * 8;
    hb8[S] = cvt_h8(*(const f32x4*)(p), *(const f32x4*)(p + 4));
  }
  __syncthreads();

  half8* wl8w = (half8*)wlds + (w * 12) * 64;   // this wave's private region

  switch (w) {   // wave-uniform branch; all paths execute identical barrier counts
    case 0: rnn_core<0>(W_hh, xp, hb8, wl8w, g, L); break;
    case 1: rnn_core<1>(W_hh, xp, hb8, wl8w, g, L); break;
    case 2: rnn_core<2>(W_hh, xp, hb8, wl8w, g, L); break;
    case 3: rnn_core<3>(W_hh, xp, hb8, wl8w, g, L); break;
    case 4: rnn_core<4>(W_hh, xp, hb8, wl8w, g, L); break;
    case 5: rnn_core<5>(W_hh, xp, hb8, wl8w, g, L); break;
    case 6: rnn_core<6>(W_hh, xp, hb8, wl8w, g, L); break;
    default: rnn_core<7>(W_hh, xp, hb8, wl8w, g, L); break;
  }

  // ---- output 1: h_last (1,B,H) fp32 at out+4096 (final h in buffer 0) ----
  const half8* hf = hb8;   // buffer 0 (T even)
  #pragma unroll
  for (int u = 0; u < 2; ++u) {
    const int ri = tid + u * 512;
    const int k8 = ri >> 4, nb = ri & 15;
    const half8 v = hf[k8 * 16 + nb];
    float* dst = out + 4096 + (g * 16 + nb) * H_ + k8 * 8;
    #pragma unroll
    for (int e = 0; e < 8; ++e) dst[e] = (float)v[e];
  }
  // ---- output 0: FC (reuse wlds as fp32 [16][513]) ----
  __syncthreads();
  float* wfcf = (float*)wlds;
  #pragma unroll
  for (int u = 0; u < 16; ++u) {
    const int idx = tid + u * 512;
    wfcf[(idx >> 9) * 513 + (idx & 511)] = W_fc[idx];
  }
  __syncthreads();
  if (tid < 256) {
    const int bl = tid >> 4, o = tid & 15;
    float s = 0.f;
    #pragma unroll 8
    for (int k8 = 0; k8 < 64; ++k8) {
      const half8 v = hf[k8 * 16 + bl];
      #pragma unroll
      for (int e = 0; e < 8; ++e) s += (float)v[e] * wfcf[o * 513 + k8 * 8 + e];
    }
    out[(g * 16 + bl) * 16 + o] = s + b_fc[o];
  }
}

extern "C" void kernel_launch(void* const* d_in, const int* in_sizes, int n_in,
                              void* d_out, int out_size, void* d_ws, size_t ws_size,
                              hipStream_t stream) {
  const float* x    = (const float*)d_in[0];
  const float* h0   = (const float*)d_in[1];
  const float* W_ih = (const float*)d_in[2];
  const float* W_hh = (const float*)d_in[3];
  const float* b_ih = (const float*)d_in[4];
  const float* b_hh = (const float*)d_in[5];
  const float* W_fc = (const float*)d_in[6];
  const float* b_fc = (const float*)d_in[7];
  float* out = (float*)d_out;

  _Float16* xp = (_Float16*)d_ws;   // 134 MB f16 workspace

  xp_prepass<<<dim3(512), dim3(256), 0, stream>>>(x, W_ih, b_ih, b_hh, xp);
  rnn_persist<<<dim3(16), dim3(512), 0, stream>>>(h0, W_hh, W_fc, b_fc, out, xp);
}